// Round 4
// baseline (426.895 us; speedup 1.0000x reference)
//
#include <hip/hip_runtime.h>

#define B   8
#define C   256
#define N   4096
#define H   8
#define D   64
#define HID 512
#define SCALE 0.125f

typedef __attribute__((ext_vector_type(8))) __bf16 bf16x8;
typedef __attribute__((ext_vector_type(4))) float f32x4;

__device__ __forceinline__ ushort f2bf(float f) {
  union { float f; unsigned u; } v; v.f = f;
  unsigned r = v.u + 0x7FFFu + ((v.u >> 16) & 1u);
  return (ushort)(r >> 16);
}

__device__ __forceinline__ f32x4 mfma16(bf16x8 a, bf16x8 b, f32x4 c) {
  return __builtin_amdgcn_mfma_f32_16x16x32_bf16(a, b, c, 0, 0, 0);
}

// ---------------------------------------------------------------------------
// Transpose+cast: src fp32 [b][C][N] -> dst bf16 [b][N][C].  64x64 tiles.
// blockIdx.z == 8 slice: cast Wk/Wv fp32->bf16 instead (fused dispatch).
// ---------------------------------------------------------------------------
__global__ __launch_bounds__(256) void transpose_cast_kernel(
    const float* __restrict__ src, ushort* __restrict__ dst,
    const float* __restrict__ Wk, const float* __restrict__ Wv,
    ushort* __restrict__ wk_bf, ushort* __restrict__ wv_bf) {
  const int tid = threadIdx.x;
  if (blockIdx.z == 8) {            // weight-cast slice (128 blocks used)
    const int id = blockIdx.y * 64 + blockIdx.x;
    if (id < 128) {
      const int t = (id * 256 + tid) * 4;   // HID*C = 131072 elems
      const float4 a = *(const float4*)(Wk + t);
      const float4 b = *(const float4*)(Wv + t);
      ushort4 ra, rb;
      ra.x = f2bf(a.x); ra.y = f2bf(a.y); ra.z = f2bf(a.z); ra.w = f2bf(a.w);
      rb.x = f2bf(b.x); rb.y = f2bf(b.y); rb.z = f2bf(b.z); rb.w = f2bf(b.w);
      *(ushort4*)(wk_bf + t) = ra;
      *(ushort4*)(wv_bf + t) = rb;
    }
    return;
  }
  __shared__ float tile[64 * 65];
  const int l0 = blockIdx.x * 64, r0 = blockIdx.y * 64, b = blockIdx.z;
  const int rr = tid >> 4, c4 = (tid & 15) << 2;
  const float* sp = src + ((size_t)b * C + r0) * N + l0;
#pragma unroll
  for (int p = 0; p < 4; ++p) {
    const float4 v = *(const float4*)(sp + (size_t)(rr + p * 16) * N + c4);
    float* tp = tile + (rr + p * 16) * 65 + c4;
    tp[0] = v.x; tp[1] = v.y; tp[2] = v.z; tp[3] = v.w;
  }
  __syncthreads();
  const int lr = tid >> 2, rb = (tid & 3) << 4;
  uint pk[8];
#pragma unroll
  for (int k = 0; k < 16; k += 2) {
    const uint lo = f2bf(tile[(rb + k) * 65 + lr]);
    const uint hi = f2bf(tile[(rb + k + 1) * 65 + lr]);
    pk[k >> 1] = lo | (hi << 16);
  }
  ushort* dp = dst + ((size_t)b * N + l0 + lr) * C + r0 + rb;
  *(uint4*)dp = *(uint4*)pk;
  *(uint4*)(dp + 8) = *(uint4*)(pk + 4);
}

// ---------------------------------------------------------------------------
// Kernel 1 (MFMA): per (m-tile of 256, h, b), looped over two 128-m chunks:
//   proj: D[m][d] = ctxt-rows(m) x Wk/Wv-rows(d); P = exp(K)
//   staging: shared P[64][128] + V[64][128] bf16 (XOR-swizzled), 32 KB
//   ctx: each wave computes a disjoint 32x32 (d,e) quadrant over all 128 m
//   -> direct global quadrant store, no cross-wave reduction, no atomics.
// ---------------------------------------------------------------------------
__global__ __launch_bounds__(256, 4) void kv_mfma_kernel(
    const ushort* __restrict__ ctxt_bf,   // [B][N][C] bf16
    const ushort* __restrict__ wk_bf,     // [HID][C]
    const ushort* __restrict__ wv_bf,
    float* __restrict__ ctx_part,         // [B*H][16][64(d)][64(e)]
    float* __restrict__ z_part)           // [B*H][16][64]
{
  __shared__ __align__(16) ushort pv[2 * 64 * 128];   // P | V, 32 KB
  __shared__ float zred[4][64];
  const int mt = blockIdx.x, h = blockIdx.y, b = blockIdx.z;
  const int tid = threadIdx.x;
  const int w = tid >> 6, lane = tid & 63;
  const int col = lane & 15, quad = lane >> 4;
  const int dh = w >> 1, eh = w & 1;

  const ushort* wkp = wk_bf + (size_t)(h * 64) * C;
  const ushort* wvp = wv_bf + (size_t)(h * 64) * C;
  ushort* Pb = pv;
  ushort* Vb = pv + 64 * 128;

  const f32x4 z4 = {0.f, 0.f, 0.f, 0.f};
  f32x4 cacc[2][2];
#pragma unroll
  for (int i = 0; i < 2; ++i)
#pragma unroll
    for (int j = 0; j < 2; ++j) cacc[i][j] = z4;
  float zacc[4] = {0.f, 0.f, 0.f, 0.f};

  for (int ms = 0; ms < 2; ++ms) {
    const size_t m_base = (size_t)mt * 256 + ms * 128 + w * 32;
    const ushort* cb = ctxt_bf + ((size_t)b * N + m_base) * C;

    // ---- merged K+V projection: D[m(32)][d(64)] per wave ----
    f32x4 kacc[2][4], vacc[2][4];
#pragma unroll
    for (int i = 0; i < 2; ++i)
#pragma unroll
      for (int j = 0; j < 4; ++j) { kacc[i][j] = z4; vacc[i][j] = z4; }
#pragma unroll
    for (int kk = 0; kk < 8; ++kk) {
      const int ko = kk * 32 + quad * 8;
      bf16x8 a[2], bk[4], bv[4];
#pragma unroll
      for (int i = 0; i < 2; ++i) a[i] = *(const bf16x8*)(cb + (size_t)(i * 16 + col) * C + ko);
#pragma unroll
      for (int j = 0; j < 4; ++j) bk[j] = *(const bf16x8*)(wkp + (size_t)(j * 16 + col) * C + ko);
#pragma unroll
      for (int j = 0; j < 4; ++j) bv[j] = *(const bf16x8*)(wvp + (size_t)(j * 16 + col) * C + ko);
#pragma unroll
      for (int i = 0; i < 2; ++i)
#pragma unroll
        for (int j = 0; j < 4; ++j) {
          kacc[i][j] = mfma16(a[i], bk[j], kacc[i][j]);
          vacc[i][j] = mfma16(a[i], bv[j], vacc[i][j]);
        }
    }

    if (ms) __syncthreads();   // prev chunk's ctx reads done before restaging

    // ---- exp + staging (b64 writes, XOR swizzle), Z accumulate ----
#pragma unroll
    for (int i = 0; i < 2; ++i) {
      const int mg = w * 4 + i * 2 + (quad >> 1);   // m>>3 group within 128
      const int sub = (quad & 1) << 2;
#pragma unroll
      for (int j = 0; j < 4; ++j) {
        const int d = j * 16 + col;                 // d&15 == col
        const int off = d * 128 + (((mg ^ col) << 3) | sub);
        const f32x4 k4 = kacc[i][j];
        const float e0 = __expf(k4[0]), e1 = __expf(k4[1]);
        const float e2 = __expf(k4[2]), e3 = __expf(k4[3]);
        zacc[j] += (e0 + e1) + (e2 + e3);
        ushort4 pk; pk.x = f2bf(e0); pk.y = f2bf(e1); pk.z = f2bf(e2); pk.w = f2bf(e3);
        const f32x4 v4 = vacc[i][j];
        ushort4 vk; vk.x = f2bf(v4[0]); vk.y = f2bf(v4[1]); vk.z = f2bf(v4[2]); vk.w = f2bf(v4[3]);
        *(ushort4*)(Pb + off) = pk;
        *(ushort4*)(Vb + off) = vk;
      }
    }
    __syncthreads();

    // ---- ctx quadrant: wave (dh,eh) computes d in dh*32+[0,32), e in eh*32+[0,32) over 128 m
#pragma unroll
    for (int kk = 0; kk < 4; ++kk) {
      const int mg = kk * 4 + quad;
      bf16x8 pa[2], vb[2];
#pragma unroll
      for (int i = 0; i < 2; ++i) {
        const int d = dh * 32 + i * 16 + col;
        pa[i] = *(const bf16x8*)(Pb + d * 128 + ((mg ^ col) << 3));
      }
#pragma unroll
      for (int j = 0; j < 2; ++j) {
        const int e = eh * 32 + j * 16 + col;
        vb[j] = *(const bf16x8*)(Vb + e * 128 + ((mg ^ col) << 3));
      }
#pragma unroll
      for (int i = 0; i < 2; ++i)
#pragma unroll
        for (int j = 0; j < 2; ++j) cacc[i][j] = mfma16(pa[i], vb[j], cacc[i][j]);
    }
  }

  // ---- Z: reduce over quads (shfl), then over waves (LDS) ----
#pragma unroll
  for (int j = 0; j < 4; ++j) {
    float s = zacc[j];
    s += __shfl_xor(s, 16); s += __shfl_xor(s, 32);
    if (quad == 0) zred[w][j * 16 + col] = s;
  }
  __syncthreads();

  const int bh = b * H + h;
  float* cp = ctx_part + ((size_t)bh * 16 + mt) * 4096;
#pragma unroll
  for (int i = 0; i < 2; ++i)
#pragma unroll
    for (int j = 0; j < 2; ++j)
#pragma unroll
      for (int r = 0; r < 4; ++r) {
        const int d = dh * 32 + i * 16 + quad * 4 + r;
        const int e = eh * 32 + j * 16 + col;
        cp[d * 64 + e] = cacc[i][j][r];
      }
  if (tid < 64)
    z_part[((size_t)bh * 16 + mt) * 64 + tid] =
        (zred[0][tid] + zred[1][tid]) + (zred[2][tid] + zred[3][tid]);
}

// ---------------------------------------------------------------------------
// Kernel 2 (fused combine + A): per bh:
//   ct[d][e] = sum_mt ctx_part;  zs[d] = SCALE / sum_mt z_part
//   A[b][h*64+e][c] = sum_d ct[d][e] * (zs[d] * Wq[h*64+d, c])
// ---------------------------------------------------------------------------
__global__ __launch_bounds__(256) void a_kernel(
    const float* __restrict__ ctx_part, const float* __restrict__ z_part,
    const float* __restrict__ Wq, float* __restrict__ A)   // [B][HID][C]
{
  const int bh = blockIdx.x, tid = threadIdx.x;
  const int b = bh >> 3, h = bh & 7;
  __shared__ float ct[64 * 65];   // [d][e]
  __shared__ float zs[64];
  __shared__ float wq[64 * 68];   // [d][c-tile], pre-scaled by zs[d]
  const float* cp = ctx_part + (size_t)bh * 16 * 4096;
  for (int g = tid; g < 1024; g += 256) {
    f32x4 s = {0.f, 0.f, 0.f, 0.f};
    for (int p = 0; p < 16; ++p) s += *(const f32x4*)(cp + (size_t)p * 4096 + g * 4);
    const int d = g >> 4, e = (g & 15) << 2;
    ct[d * 65 + e] = s[0]; ct[d * 65 + e + 1] = s[1];
    ct[d * 65 + e + 2] = s[2]; ct[d * 65 + e + 3] = s[3];
  }
  if (tid < 64) {
    float z = 0.f;
    for (int p = 0; p < 16; ++p) z += z_part[((size_t)bh * 16 + p) * 64 + tid];
    zs[tid] = SCALE / z;
  }
  const int e = tid & 63, co = tid >> 6;
  for (int cti = 0; cti < 4; ++cti) {
    const int c0 = cti << 6;
    __syncthreads();
    for (int r = 0; r < 16; ++r) {
      const int idx = tid + (r << 8);
      const int d = idx >> 6;
      wq[d * 68 + (idx & 63)] = Wq[(size_t)(h * 64 + d) * C + c0 + (idx & 63)] * zs[d];
    }
    __syncthreads();
    float acc[16];
#pragma unroll
    for (int k = 0; k < 16; ++k) acc[k] = 0.f;
    for (int d = 0; d < 64; ++d) {
      const float cv = ct[d * 65 + e];
      const float* wr = wq + d * 68 + co * 16;
#pragma unroll
      for (int k = 0; k < 16; ++k) acc[k] += cv * wr[k];
    }
    float* Ar = A + ((size_t)b * HID + h * 64 + e) * C + c0 + co * 16;
#pragma unroll
    for (int k = 0; k < 16; ++k) Ar[k] = acc[k];
  }
}

// ---------------------------------------------------------------------------
// Kernel 3: M[b] = Wo (256x512) @ A[b] (512x256)  -> bf16 [b][o][c]
// ---------------------------------------------------------------------------
__global__ __launch_bounds__(256) void m_kernel(
    const float* __restrict__ A, const float* __restrict__ Wo,
    ushort* __restrict__ M_bf)
{
  const int tile = blockIdx.x, b = blockIdx.y;
  const int o0 = (tile & 3) << 6, c0 = (tile >> 2) << 6;
  const int tid = threadIdx.x, tx = tid & 15, ty = tid >> 4;
  __shared__ float wo_s[16 * 68];  // [k][o]
  __shared__ float a_s[16 * 68];   // [k][c]
  float acc[4][4] = {{0.f}};
  for (int k0 = 0; k0 < HID; k0 += 16) {
    __syncthreads();
    {
      const int o = tid >> 2, koff = (tid & 3) << 2;
      const float4 w4 = *(const float4*)(Wo + (size_t)(o0 + o) * HID + k0 + koff);
      wo_s[(koff + 0) * 68 + o] = w4.x;
      wo_s[(koff + 1) * 68 + o] = w4.y;
      wo_s[(koff + 2) * 68 + o] = w4.z;
      wo_s[(koff + 3) * 68 + o] = w4.w;
      const int kk = tid >> 4, cc = (tid & 15) << 2;
      *(float4*)(a_s + kk * 68 + cc) =
          *(const float4*)(A + ((size_t)b * HID + k0 + kk) * C + c0 + cc);
    }
    __syncthreads();
#pragma unroll
    for (int kc = 0; kc < 16; ++kc) {
      const float4 wv = *(const float4*)(wo_s + kc * 68 + ty * 4);
      const float4 av = *(const float4*)(a_s + kc * 68 + tx * 4);
      const float b0 = av.x, b1 = av.y, b2 = av.z, b3 = av.w;
      acc[0][0] += wv.x * b0; acc[0][1] += wv.x * b1; acc[0][2] += wv.x * b2; acc[0][3] += wv.x * b3;
      acc[1][0] += wv.y * b0; acc[1][1] += wv.y * b1; acc[1][2] += wv.y * b2; acc[1][3] += wv.y * b3;
      acc[2][0] += wv.z * b0; acc[2][1] += wv.z * b1; acc[2][2] += wv.z * b2; acc[2][3] += wv.z * b3;
      acc[3][0] += wv.w * b0; acc[3][1] += wv.w * b1; acc[3][2] += wv.w * b2; acc[3][3] += wv.w * b3;
    }
  }
#pragma unroll
  for (int i = 0; i < 4; ++i) {
    ushort4 r;
    r.x = f2bf(acc[i][0]); r.y = f2bf(acc[i][1]);
    r.z = f2bf(acc[i][2]); r.w = f2bf(acc[i][3]);
    *(ushort4*)(M_bf + ((size_t)b * C + o0 + ty * 4 + i) * C + c0 + tx * 4) = r;
  }
}

// ---------------------------------------------------------------------------
// Kernel 4 (MFMA): out[b] = M_b (256x256) @ X_b (256x4096) + bo
// ---------------------------------------------------------------------------
__global__ __launch_bounds__(256) void out_mfma_kernel(
    const ushort* __restrict__ M_bf,     // [B][C][C] bf16
    const ushort* __restrict__ x_bf,     // [B][N][C] bf16
    const float* __restrict__ bo, float* __restrict__ out)
{
  const int nt = blockIdx.x, ot = blockIdx.y, b = blockIdx.z;
  const int tid = threadIdx.x;
  const int w = tid >> 6, lane = tid & 63;
  const int col = lane & 15, quad = lane >> 4;
  const int o0 = ot * 64;
  const size_t n_base = (size_t)nt * 256 + w * 64;
  const ushort* Ab = M_bf + ((size_t)b * C + o0 + col) * C + quad * 8;
  const ushort* Bb = x_bf + ((size_t)b * N + n_base) * C + quad * 8;

  const f32x4 z4 = {0.f, 0.f, 0.f, 0.f};
  f32x4 acc[4][4];
#pragma unroll
  for (int i = 0; i < 4; ++i)
#pragma unroll
    for (int j = 0; j < 4; ++j) acc[i][j] = z4;

#pragma unroll
  for (int kk = 0; kk < 8; ++kk) {
    bf16x8 af[4], bfz[4];
#pragma unroll
    for (int i = 0; i < 4; ++i) af[i] = *(const bf16x8*)(Ab + (size_t)(i * 16) * C + kk * 32);
#pragma unroll
    for (int j = 0; j < 4; ++j) bfz[j] = *(const bf16x8*)(Bb + (size_t)(j * 16 + col) * C + kk * 32);
#pragma unroll
    for (int i = 0; i < 4; ++i)
#pragma unroll
      for (int j = 0; j < 4; ++j) acc[i][j] = mfma16(af[i], bfz[j], acc[i][j]);
  }

#pragma unroll
  for (int i = 0; i < 4; ++i)
#pragma unroll
    for (int r = 0; r < 4; ++r) {
      const int o = o0 + i * 16 + quad * 4 + r;
      const float bias = bo[o];
      float* op = out + ((size_t)b * C + o) * N + n_base + col;
#pragma unroll
      for (int j = 0; j < 4; ++j) op[j * 16] = acc[i][j][r] + bias;
    }
}

// ---------------------------------------------------------------------------
extern "C" void kernel_launch(void* const* d_in, const int* in_sizes, int n_in,
                              void* d_out, int out_size, void* d_ws, size_t ws_size,
                              hipStream_t stream) {
  const float* x    = (const float*)d_in[0];
  const float* ctxt = (const float*)d_in[1];
  const float* Wq   = (const float*)d_in[2];
  const float* Wk   = (const float*)d_in[3];
  const float* Wv   = (const float*)d_in[4];
  const float* Wo   = (const float*)d_in[5];
  const float* bo   = (const float*)d_in[6];
  float* out = (float*)d_out;

  char* p = (char*)d_ws;
  ushort* ctxt_bf = (ushort*)p;  p += (size_t)B * N * C * 2;        // 16 MB (x_bf aliases)
  ushort* wk_bf   = (ushort*)p;  p += (size_t)HID * C * 2;
  ushort* wv_bf   = (ushort*)p;  p += (size_t)HID * C * 2;
  ushort* M_bf    = (ushort*)p;  p += (size_t)B * C * C * 2;
  float*  z_part  = (float*)p;   p += (size_t)B * H * 16 * 64 * 4;
  float*  ctx_part= (float*)p;   p += (size_t)B * H * 16 * 4096 * 4; // 16.8 MB
  float*  A       = (float*)p;   p += (size_t)B * HID * C * 4;       // 4 MB
  ushort* x_bf    = ctxt_bf;     // reused after kv_mfma_kernel

  // transpose ctxt + cast weights (fused: z=8 slice does the weight cast)
  transpose_cast_kernel<<<dim3(N / 64, C / 64, 9), 256, 0, stream>>>(
      ctxt, ctxt_bf, Wk, Wv, wk_bf, wv_bf);
  kv_mfma_kernel<<<dim3(16, H, B), 256, 0, stream>>>(ctxt_bf, wk_bf, wv_bf, ctx_part, z_part);
  transpose_cast_kernel<<<dim3(N / 64, C / 64, 8), 256, 0, stream>>>(
      x, x_bf, Wk, Wv, wk_bf, wv_bf);
  a_kernel<<<dim3(B * H), 256, 0, stream>>>(ctx_part, z_part, Wq, A);
  m_kernel<<<dim3(16, B), 256, 0, stream>>>(A, Wo, M_bf);
  out_mfma_kernel<<<dim3(N / 256, C / 64, B), 256, 0, stream>>>(M_bf, x_bf, bo, out);
}

// Round 5
// 304.405 us; speedup vs baseline: 1.4024x; 1.4024x over previous
//
#include <hip/hip_runtime.h>

#define B   8
#define C   256
#define N   4096
#define H   8
#define D   64
#define HID 512
#define SCALE 0.125f

typedef __attribute__((ext_vector_type(8))) __bf16 bf16x8;
typedef __attribute__((ext_vector_type(4))) float f32x4;

__device__ __forceinline__ ushort f2bf(float f) {
  union { float f; unsigned u; } v; v.f = f;
  unsigned r = v.u + 0x7FFFu + ((v.u >> 16) & 1u);
  return (ushort)(r >> 16);
}

__device__ __forceinline__ f32x4 mfma16(bf16x8 a, bf16x8 b, f32x4 c) {
  return __builtin_amdgcn_mfma_f32_16x16x32_bf16(a, b, c, 0, 0, 0);
}

// ---------------------------------------------------------------------------
// Transpose+cast: src fp32 [b][C][N] -> dst bf16 [b][N][C].  64x64 tiles.
// blockIdx.z == 8 slice: cast Wk/Wv fp32->bf16 instead (fused dispatch).
// ---------------------------------------------------------------------------
__global__ __launch_bounds__(256) void transpose_cast_kernel(
    const float* __restrict__ src, ushort* __restrict__ dst,
    const float* __restrict__ Wk, const float* __restrict__ Wv,
    ushort* __restrict__ wk_bf, ushort* __restrict__ wv_bf) {
  const int tid = threadIdx.x;
  if (blockIdx.z == 8) {            // weight-cast slice (128 blocks used)
    const int id = blockIdx.y * 64 + blockIdx.x;
    if (id < 128) {
      const int t = (id * 256 + tid) * 4;   // HID*C = 131072 elems
      const float4 a = *(const float4*)(Wk + t);
      const float4 b = *(const float4*)(Wv + t);
      ushort4 ra, rb;
      ra.x = f2bf(a.x); ra.y = f2bf(a.y); ra.z = f2bf(a.z); ra.w = f2bf(a.w);
      rb.x = f2bf(b.x); rb.y = f2bf(b.y); rb.z = f2bf(b.z); rb.w = f2bf(b.w);
      *(ushort4*)(wk_bf + t) = ra;
      *(ushort4*)(wv_bf + t) = rb;
    }
    return;
  }
  __shared__ float tile[64 * 65];
  const int l0 = blockIdx.x * 64, r0 = blockIdx.y * 64, b = blockIdx.z;
  const int rr = tid >> 4, c4 = (tid & 15) << 2;
  const float* sp = src + ((size_t)b * C + r0) * N + l0;
#pragma unroll
  for (int p = 0; p < 4; ++p) {
    const float4 v = *(const float4*)(sp + (size_t)(rr + p * 16) * N + c4);
    float* tp = tile + (rr + p * 16) * 65 + c4;
    tp[0] = v.x; tp[1] = v.y; tp[2] = v.z; tp[3] = v.w;
  }
  __syncthreads();
  const int lr = tid >> 2, rb = (tid & 3) << 4;
  uint pk[8];
#pragma unroll
  for (int k = 0; k < 16; k += 2) {
    const uint lo = f2bf(tile[(rb + k) * 65 + lr]);
    const uint hi = f2bf(tile[(rb + k + 1) * 65 + lr]);
    pk[k >> 1] = lo | (hi << 16);
  }
  ushort* dp = dst + ((size_t)b * N + l0 + lr) * C + r0 + rb;
  *(uint4*)dp = *(uint4*)pk;
  *(uint4*)(dp + 8) = *(uint4*)(pk + 4);
}

// ---------------------------------------------------------------------------
// Kernel 1 (MFMA): per (m-tile of 256, h, b), looped over two 128-m chunks:
//   proj: D[m][d] = ctxt-rows(m) x Wk/Wv-rows(d); P = exp(K)
//   staging: shared P[64][128] + V[64][128] bf16 (XOR-swizzled), 32 KB
//   ctx: each wave computes a disjoint 32x32 (d,e) quadrant over all 128 m
//   -> direct global quadrant store, no cross-wave reduction, no atomics.
// NOTE: launch_bounds min-waves MUST stay 2 — R4's (256,4) clamped VGPRs to
// 64 and spilled ~660 MB/dispatch to scratch (225 us).  (256,2) -> ~120 VGPRs.
// ---------------------------------------------------------------------------
__global__ __launch_bounds__(256, 2) void kv_mfma_kernel(
    const ushort* __restrict__ ctxt_bf,   // [B][N][C] bf16
    const ushort* __restrict__ wk_bf,     // [HID][C]
    const ushort* __restrict__ wv_bf,
    float* __restrict__ ctx_part,         // [B*H][16][64(d)][64(e)]
    float* __restrict__ z_part)           // [B*H][16][64]
{
  __shared__ __align__(16) ushort pv[2 * 64 * 128];   // P | V, 32 KB
  __shared__ float zred[4][64];
  const int mt = blockIdx.x, h = blockIdx.y, b = blockIdx.z;
  const int tid = threadIdx.x;
  const int w = tid >> 6, lane = tid & 63;
  const int col = lane & 15, quad = lane >> 4;
  const int dh = w >> 1, eh = w & 1;

  const ushort* wkp = wk_bf + (size_t)(h * 64) * C;
  const ushort* wvp = wv_bf + (size_t)(h * 64) * C;
  ushort* Pb = pv;
  ushort* Vb = pv + 64 * 128;

  const f32x4 z4 = {0.f, 0.f, 0.f, 0.f};
  f32x4 cacc[2][2];
#pragma unroll
  for (int i = 0; i < 2; ++i)
#pragma unroll
    for (int j = 0; j < 2; ++j) cacc[i][j] = z4;
  float zacc[4] = {0.f, 0.f, 0.f, 0.f};

  for (int ms = 0; ms < 2; ++ms) {
    const size_t m_base = (size_t)mt * 256 + ms * 128 + w * 32;
    const ushort* cb = ctxt_bf + ((size_t)b * N + m_base) * C;

    // ---- merged K+V projection: D[m(32)][d(64)] per wave ----
    f32x4 kacc[2][4], vacc[2][4];
#pragma unroll
    for (int i = 0; i < 2; ++i)
#pragma unroll
      for (int j = 0; j < 4; ++j) { kacc[i][j] = z4; vacc[i][j] = z4; }
#pragma unroll
    for (int kk = 0; kk < 8; ++kk) {
      const int ko = kk * 32 + quad * 8;
      bf16x8 a[2], bk[4], bv[4];
#pragma unroll
      for (int i = 0; i < 2; ++i) a[i] = *(const bf16x8*)(cb + (size_t)(i * 16 + col) * C + ko);
#pragma unroll
      for (int j = 0; j < 4; ++j) bk[j] = *(const bf16x8*)(wkp + (size_t)(j * 16 + col) * C + ko);
#pragma unroll
      for (int j = 0; j < 4; ++j) bv[j] = *(const bf16x8*)(wvp + (size_t)(j * 16 + col) * C + ko);
#pragma unroll
      for (int i = 0; i < 2; ++i)
#pragma unroll
        for (int j = 0; j < 4; ++j) {
          kacc[i][j] = mfma16(a[i], bk[j], kacc[i][j]);
          vacc[i][j] = mfma16(a[i], bv[j], vacc[i][j]);
        }
    }

    if (ms) __syncthreads();   // prev chunk's ctx reads done before restaging

    // ---- exp + staging (b64 writes, XOR swizzle), Z accumulate ----
#pragma unroll
    for (int i = 0; i < 2; ++i) {
      const int mg = w * 4 + i * 2 + (quad >> 1);   // m>>3 group within 128
      const int sub = (quad & 1) << 2;
#pragma unroll
      for (int j = 0; j < 4; ++j) {
        const int d = j * 16 + col;                 // d&15 == col
        const int off = d * 128 + (((mg ^ col) << 3) | sub);
        const f32x4 k4 = kacc[i][j];
        const float e0 = __expf(k4[0]), e1 = __expf(k4[1]);
        const float e2 = __expf(k4[2]), e3 = __expf(k4[3]);
        zacc[j] += (e0 + e1) + (e2 + e3);
        ushort4 pk; pk.x = f2bf(e0); pk.y = f2bf(e1); pk.z = f2bf(e2); pk.w = f2bf(e3);
        const f32x4 v4 = vacc[i][j];
        ushort4 vk; vk.x = f2bf(v4[0]); vk.y = f2bf(v4[1]); vk.z = f2bf(v4[2]); vk.w = f2bf(v4[3]);
        *(ushort4*)(Pb + off) = pk;
        *(ushort4*)(Vb + off) = vk;
      }
    }
    __syncthreads();

    // ---- ctx quadrant: wave (dh,eh) computes d in dh*32+[0,32), e in eh*32+[0,32) over 128 m
#pragma unroll
    for (int kk = 0; kk < 4; ++kk) {
      const int mg = kk * 4 + quad;
      bf16x8 pa[2], vb[2];
#pragma unroll
      for (int i = 0; i < 2; ++i) {
        const int d = dh * 32 + i * 16 + col;
        pa[i] = *(const bf16x8*)(Pb + d * 128 + ((mg ^ col) << 3));
      }
#pragma unroll
      for (int j = 0; j < 2; ++j) {
        const int e = eh * 32 + j * 16 + col;
        vb[j] = *(const bf16x8*)(Vb + e * 128 + ((mg ^ col) << 3));
      }
#pragma unroll
      for (int i = 0; i < 2; ++i)
#pragma unroll
        for (int j = 0; j < 2; ++j) cacc[i][j] = mfma16(pa[i], vb[j], cacc[i][j]);
    }
  }

  // ---- Z: reduce over quads (shfl), then over waves (LDS) ----
#pragma unroll
  for (int j = 0; j < 4; ++j) {
    float s = zacc[j];
    s += __shfl_xor(s, 16); s += __shfl_xor(s, 32);
    if (quad == 0) zred[w][j * 16 + col] = s;
  }
  __syncthreads();

  const int bh = b * H + h;
  float* cp = ctx_part + ((size_t)bh * 16 + mt) * 4096;
#pragma unroll
  for (int i = 0; i < 2; ++i)
#pragma unroll
    for (int j = 0; j < 2; ++j)
#pragma unroll
      for (int r = 0; r < 4; ++r) {
        const int d = dh * 32 + i * 16 + quad * 4 + r;
        const int e = eh * 32 + j * 16 + col;
        cp[d * 64 + e] = cacc[i][j][r];
      }
  if (tid < 64)
    z_part[((size_t)bh * 16 + mt) * 64 + tid] =
        (zred[0][tid] + zred[1][tid]) + (zred[2][tid] + zred[3][tid]);
}

// ---------------------------------------------------------------------------
// Kernel 2 (fused combine + A): per bh:
//   ct[d][e] = sum_mt ctx_part;  zs[d] = SCALE / sum_mt z_part
//   A[b][h*64+e][c] = sum_d ct[d][e] * (zs[d] * Wq[h*64+d, c])
// ---------------------------------------------------------------------------
__global__ __launch_bounds__(256) void a_kernel(
    const float* __restrict__ ctx_part, const float* __restrict__ z_part,
    const float* __restrict__ Wq, float* __restrict__ A)   // [B][HID][C]
{
  const int bh = blockIdx.x, tid = threadIdx.x;
  const int b = bh >> 3, h = bh & 7;
  __shared__ float ct[64 * 65];   // [d][e]
  __shared__ float zs[64];
  __shared__ float wq[64 * 68];   // [d][c-tile], pre-scaled by zs[d]
  const float* cp = ctx_part + (size_t)bh * 16 * 4096;
  for (int g = tid; g < 1024; g += 256) {
    f32x4 s = {0.f, 0.f, 0.f, 0.f};
    for (int p = 0; p < 16; ++p) s += *(const f32x4*)(cp + (size_t)p * 4096 + g * 4);
    const int d = g >> 4, e = (g & 15) << 2;
    ct[d * 65 + e] = s[0]; ct[d * 65 + e + 1] = s[1];
    ct[d * 65 + e + 2] = s[2]; ct[d * 65 + e + 3] = s[3];
  }
  if (tid < 64) {
    float z = 0.f;
    for (int p = 0; p < 16; ++p) z += z_part[((size_t)bh * 16 + p) * 64 + tid];
    zs[tid] = SCALE / z;
  }
  const int e = tid & 63, co = tid >> 6;
  for (int cti = 0; cti < 4; ++cti) {
    const int c0 = cti << 6;
    __syncthreads();
    for (int r = 0; r < 16; ++r) {
      const int idx = tid + (r << 8);
      const int d = idx >> 6;
      wq[d * 68 + (idx & 63)] = Wq[(size_t)(h * 64 + d) * C + c0 + (idx & 63)] * zs[d];
    }
    __syncthreads();
    float acc[16];
#pragma unroll
    for (int k = 0; k < 16; ++k) acc[k] = 0.f;
    for (int d = 0; d < 64; ++d) {
      const float cv = ct[d * 65 + e];
      const float* wr = wq + d * 68 + co * 16;
#pragma unroll
      for (int k = 0; k < 16; ++k) acc[k] += cv * wr[k];
    }
    float* Ar = A + ((size_t)b * HID + h * 64 + e) * C + c0 + co * 16;
#pragma unroll
    for (int k = 0; k < 16; ++k) Ar[k] = acc[k];
  }
}

// ---------------------------------------------------------------------------
// Kernel 3: M[b] = Wo (256x512) @ A[b] (512x256)  -> bf16 [b][o][c]
// ---------------------------------------------------------------------------
__global__ __launch_bounds__(256) void m_kernel(
    const float* __restrict__ A, const float* __restrict__ Wo,
    ushort* __restrict__ M_bf)
{
  const int tile = blockIdx.x, b = blockIdx.y;
  const int o0 = (tile & 3) << 6, c0 = (tile >> 2) << 6;
  const int tid = threadIdx.x, tx = tid & 15, ty = tid >> 4;
  __shared__ float wo_s[16 * 68];  // [k][o]
  __shared__ float a_s[16 * 68];   // [k][c]
  float acc[4][4] = {{0.f}};
  for (int k0 = 0; k0 < HID; k0 += 16) {
    __syncthreads();
    {
      const int o = tid >> 2, koff = (tid & 3) << 2;
      const float4 w4 = *(const float4*)(Wo + (size_t)(o0 + o) * HID + k0 + koff);
      wo_s[(koff + 0) * 68 + o] = w4.x;
      wo_s[(koff + 1) * 68 + o] = w4.y;
      wo_s[(koff + 2) * 68 + o] = w4.z;
      wo_s[(koff + 3) * 68 + o] = w4.w;
      const int kk = tid >> 4, cc = (tid & 15) << 2;
      *(float4*)(a_s + kk * 68 + cc) =
          *(const float4*)(A + ((size_t)b * HID + k0 + kk) * C + c0 + cc);
    }
    __syncthreads();
#pragma unroll
    for (int kc = 0; kc < 16; ++kc) {
      const float4 wv = *(const float4*)(wo_s + kc * 68 + ty * 4);
      const float4 av = *(const float4*)(a_s + kc * 68 + tx * 4);
      const float b0 = av.x, b1 = av.y, b2 = av.z, b3 = av.w;
      acc[0][0] += wv.x * b0; acc[0][1] += wv.x * b1; acc[0][2] += wv.x * b2; acc[0][3] += wv.x * b3;
      acc[1][0] += wv.y * b0; acc[1][1] += wv.y * b1; acc[1][2] += wv.y * b2; acc[1][3] += wv.y * b3;
      acc[2][0] += wv.z * b0; acc[2][1] += wv.z * b1; acc[2][2] += wv.z * b2; acc[2][3] += wv.z * b3;
      acc[3][0] += wv.w * b0; acc[3][1] += wv.w * b1; acc[3][2] += wv.w * b2; acc[3][3] += wv.w * b3;
    }
  }
#pragma unroll
  for (int i = 0; i < 4; ++i) {
    ushort4 r;
    r.x = f2bf(acc[i][0]); r.y = f2bf(acc[i][1]);
    r.z = f2bf(acc[i][2]); r.w = f2bf(acc[i][3]);
    *(ushort4*)(M_bf + ((size_t)b * C + o0 + ty * 4 + i) * C + c0 + tx * 4) = r;
  }
}

// ---------------------------------------------------------------------------
// Kernel 4 (MFMA): out[b] = M_b (256x256) @ X_b (256x4096) + bo
// ---------------------------------------------------------------------------
__global__ __launch_bounds__(256) void out_mfma_kernel(
    const ushort* __restrict__ M_bf,     // [B][C][C] bf16
    const ushort* __restrict__ x_bf,     // [B][N][C] bf16
    const float* __restrict__ bo, float* __restrict__ out)
{
  const int nt = blockIdx.x, ot = blockIdx.y, b = blockIdx.z;
  const int tid = threadIdx.x;
  const int w = tid >> 6, lane = tid & 63;
  const int col = lane & 15, quad = lane >> 4;
  const int o0 = ot * 64;
  const size_t n_base = (size_t)nt * 256 + w * 64;
  const ushort* Ab = M_bf + ((size_t)b * C + o0 + col) * C + quad * 8;
  const ushort* Bb = x_bf + ((size_t)b * N + n_base) * C + quad * 8;

  const f32x4 z4 = {0.f, 0.f, 0.f, 0.f};
  f32x4 acc[4][4];
#pragma unroll
  for (int i = 0; i < 4; ++i)
#pragma unroll
    for (int j = 0; j < 4; ++j) acc[i][j] = z4;

#pragma unroll
  for (int kk = 0; kk < 8; ++kk) {
    bf16x8 af[4], bfz[4];
#pragma unroll
    for (int i = 0; i < 4; ++i) af[i] = *(const bf16x8*)(Ab + (size_t)(i * 16) * C + kk * 32);
#pragma unroll
    for (int j = 0; j < 4; ++j) bfz[j] = *(const bf16x8*)(Bb + (size_t)(j * 16 + col) * C + kk * 32);
#pragma unroll
    for (int i = 0; i < 4; ++i)
#pragma unroll
      for (int j = 0; j < 4; ++j) acc[i][j] = mfma16(af[i], bfz[j], acc[i][j]);
  }

#pragma unroll
  for (int i = 0; i < 4; ++i)
#pragma unroll
    for (int r = 0; r < 4; ++r) {
      const int o = o0 + i * 16 + quad * 4 + r;
      const float bias = bo[o];
      float* op = out + ((size_t)b * C + o) * N + n_base + col;
#pragma unroll
      for (int j = 0; j < 4; ++j) op[j * 16] = acc[i][j][r] + bias;
    }
}

// ---------------------------------------------------------------------------
extern "C" void kernel_launch(void* const* d_in, const int* in_sizes, int n_in,
                              void* d_out, int out_size, void* d_ws, size_t ws_size,
                              hipStream_t stream) {
  const float* x    = (const float*)d_in[0];
  const float* ctxt = (const float*)d_in[1];
  const float* Wq   = (const float*)d_in[2];
  const float* Wk   = (const float*)d_in[3];
  const float* Wv   = (const float*)d_in[4];
  const float* Wo   = (const float*)d_in[5];
  const float* bo   = (const float*)d_in[6];
  float* out = (float*)d_out;

  char* p = (char*)d_ws;
  ushort* ctxt_bf = (ushort*)p;  p += (size_t)B * N * C * 2;        // 16 MB (x_bf aliases)
  ushort* wk_bf   = (ushort*)p;  p += (size_t)HID * C * 2;
  ushort* wv_bf   = (ushort*)p;  p += (size_t)HID * C * 2;
  ushort* M_bf    = (ushort*)p;  p += (size_t)B * C * C * 2;
  float*  z_part  = (float*)p;   p += (size_t)B * H * 16 * 64 * 4;
  float*  ctx_part= (float*)p;   p += (size_t)B * H * 16 * 4096 * 4; // 16.8 MB
  float*  A       = (float*)p;   p += (size_t)B * HID * C * 4;       // 4 MB
  ushort* x_bf    = ctxt_bf;     // reused after kv_mfma_kernel

  // transpose ctxt + cast weights (fused: z=8 slice does the weight cast)
  transpose_cast_kernel<<<dim3(N / 64, C / 64, 9), 256, 0, stream>>>(
      ctxt, ctxt_bf, Wk, Wv, wk_bf, wv_bf);
  kv_mfma_kernel<<<dim3(16, H, B), 256, 0, stream>>>(ctxt_bf, wk_bf, wv_bf, ctx_part, z_part);
  transpose_cast_kernel<<<dim3(N / 64, C / 64, 8), 256, 0, stream>>>(
      x, x_bf, Wk, Wv, wk_bf, wv_bf);
  a_kernel<<<dim3(B * H), 256, 0, stream>>>(ctx_part, z_part, Wq, A);
  m_kernel<<<dim3(16, B), 256, 0, stream>>>(A, Wo, M_bf);
  out_mfma_kernel<<<dim3(N / 256, C / 64, B), 256, 0, stream>>>(M_bf, x_bf, bo, out);
}

// Round 6
// 274.448 us; speedup vs baseline: 1.5555x; 1.1092x over previous
//
#include <hip/hip_runtime.h>

#define B   8
#define C   256
#define N   4096
#define H   8
#define D   64
#define HID 512
#define SCALE 0.125f

typedef __attribute__((ext_vector_type(8))) __bf16 bf16x8;
typedef __attribute__((ext_vector_type(4))) float f32x4;

__device__ __forceinline__ ushort f2bf(float f) {
  union { float f; unsigned u; } v; v.f = f;
  unsigned r = v.u + 0x7FFFu + ((v.u >> 16) & 1u);
  return (ushort)(r >> 16);
}

__device__ __forceinline__ f32x4 mfma16(bf16x8 a, bf16x8 b, f32x4 c) {
  return __builtin_amdgcn_mfma_f32_16x16x32_bf16(a, b, c, 0, 0, 0);
}

// ---------------------------------------------------------------------------
// Transpose+cast: src fp32 [b][C][N] -> dst bf16 [b][N][C].  64x64 tiles.
// blockIdx.z == 8 slice: cast Wk/Wv fp32->bf16 instead (fused dispatch).
// ---------------------------------------------------------------------------
__global__ __launch_bounds__(256) void transpose_cast_kernel(
    const float* __restrict__ src, ushort* __restrict__ dst,
    const float* __restrict__ Wk, const float* __restrict__ Wv,
    ushort* __restrict__ wk_bf, ushort* __restrict__ wv_bf) {
  const int tid = threadIdx.x;
  if (blockIdx.z == 8) {            // weight-cast slice (128 blocks used)
    const int id = blockIdx.y * 64 + blockIdx.x;
    if (id < 128) {
      const int t = (id * 256 + tid) * 4;   // HID*C = 131072 elems
      const float4 a = *(const float4*)(Wk + t);
      const float4 b = *(const float4*)(Wv + t);
      ushort4 ra, rb;
      ra.x = f2bf(a.x); ra.y = f2bf(a.y); ra.z = f2bf(a.z); ra.w = f2bf(a.w);
      rb.x = f2bf(b.x); rb.y = f2bf(b.y); rb.z = f2bf(b.z); rb.w = f2bf(b.w);
      *(ushort4*)(wk_bf + t) = ra;
      *(ushort4*)(wv_bf + t) = rb;
    }
    return;
  }
  __shared__ float tile[64 * 65];
  const int l0 = blockIdx.x * 64, r0 = blockIdx.y * 64, b = blockIdx.z;
  const int rr = tid >> 4, c4 = (tid & 15) << 2;
  const float* sp = src + ((size_t)b * C + r0) * N + l0;
#pragma unroll
  for (int p = 0; p < 4; ++p) {
    const float4 v = *(const float4*)(sp + (size_t)(rr + p * 16) * N + c4);
    float* tp = tile + (rr + p * 16) * 65 + c4;
    tp[0] = v.x; tp[1] = v.y; tp[2] = v.z; tp[3] = v.w;
  }
  __syncthreads();
  const int lr = tid >> 2, rb = (tid & 3) << 4;
  uint pk[8];
#pragma unroll
  for (int k = 0; k < 16; k += 2) {
    const uint lo = f2bf(tile[(rb + k) * 65 + lr]);
    const uint hi = f2bf(tile[(rb + k + 1) * 65 + lr]);
    pk[k >> 1] = lo | (hi << 16);
  }
  ushort* dp = dst + ((size_t)b * N + l0 + lr) * C + r0 + rb;
  *(uint4*)dp = *(uint4*)pk;
  *(uint4*)(dp + 8) = *(uint4*)(pk + 4);
}

// ---------------------------------------------------------------------------
// Kernel 1 (MFMA): per (m-tile of 256, h, b), looped over two 128-m chunks:
//   proj: D[m][d] = ctxt-rows(m) x Wk/Wv-rows(d); P = exp(K)
//   staging: shared P[64][128] + V[64][128] bf16 (XOR-swizzled), 32 KB
//   ctx: each wave computes a disjoint 32x32 (d,e) quadrant over all 128 m
//   -> direct global quadrant store, no cross-wave reduction, no atomics.
// NOTE: NO min-waves arg in launch_bounds!  (256,4) clamped VGPR to 64
// (R4: 660 MB spill, 225 us), (256,2) clamped to 128 (R5: 340 MB spill,
// 103 us).  Plain (256) lets the allocator take the ~160 it needs (R2
// precedent: 156 VGPR, zero spill).
// ---------------------------------------------------------------------------
__global__ __launch_bounds__(256) void kv_mfma_kernel(
    const ushort* __restrict__ ctxt_bf,   // [B][N][C] bf16
    const ushort* __restrict__ wk_bf,     // [HID][C]
    const ushort* __restrict__ wv_bf,
    float* __restrict__ ctx_part,         // [B*H][16][64(d)][64(e)]
    float* __restrict__ z_part)           // [B*H][16][64]
{
  __shared__ __align__(16) ushort pv[2 * 64 * 128];   // P | V, 32 KB
  __shared__ float zred[4][64];
  const int mt = blockIdx.x, h = blockIdx.y, b = blockIdx.z;
  const int tid = threadIdx.x;
  const int w = tid >> 6, lane = tid & 63;
  const int col = lane & 15, quad = lane >> 4;
  const int dh = w >> 1, eh = w & 1;

  const ushort* wkp = wk_bf + (size_t)(h * 64) * C;
  const ushort* wvp = wv_bf + (size_t)(h * 64) * C;
  ushort* Pb = pv;
  ushort* Vb = pv + 64 * 128;

  const f32x4 z4 = {0.f, 0.f, 0.f, 0.f};
  f32x4 cacc[2][2];
#pragma unroll
  for (int i = 0; i < 2; ++i)
#pragma unroll
    for (int j = 0; j < 2; ++j) cacc[i][j] = z4;
  float zacc[4] = {0.f, 0.f, 0.f, 0.f};

  for (int ms = 0; ms < 2; ++ms) {
    const size_t m_base = (size_t)mt * 256 + ms * 128 + w * 32;
    const ushort* cb = ctxt_bf + ((size_t)b * N + m_base) * C;

    // ---- merged K+V projection: D[m(32)][d(64)] per wave ----
    f32x4 kacc[2][4], vacc[2][4];
#pragma unroll
    for (int i = 0; i < 2; ++i)
#pragma unroll
      for (int j = 0; j < 4; ++j) { kacc[i][j] = z4; vacc[i][j] = z4; }
#pragma unroll
    for (int kk = 0; kk < 8; ++kk) {
      const int ko = kk * 32 + quad * 8;
      bf16x8 a[2], bk[4], bv[4];
#pragma unroll
      for (int i = 0; i < 2; ++i) a[i] = *(const bf16x8*)(cb + (size_t)(i * 16 + col) * C + ko);
#pragma unroll
      for (int j = 0; j < 4; ++j) bk[j] = *(const bf16x8*)(wkp + (size_t)(j * 16 + col) * C + ko);
#pragma unroll
      for (int j = 0; j < 4; ++j) bv[j] = *(const bf16x8*)(wvp + (size_t)(j * 16 + col) * C + ko);
#pragma unroll
      for (int i = 0; i < 2; ++i)
#pragma unroll
        for (int j = 0; j < 4; ++j) {
          kacc[i][j] = mfma16(a[i], bk[j], kacc[i][j]);
          vacc[i][j] = mfma16(a[i], bv[j], vacc[i][j]);
        }
    }

    if (ms) __syncthreads();   // prev chunk's ctx reads done before restaging

    // ---- exp + staging (b64 writes, XOR swizzle), Z accumulate ----
#pragma unroll
    for (int i = 0; i < 2; ++i) {
      const int mg = w * 4 + i * 2 + (quad >> 1);   // m>>3 group within 128
      const int sub = (quad & 1) << 2;
#pragma unroll
      for (int j = 0; j < 4; ++j) {
        const int d = j * 16 + col;                 // d&15 == col
        const int off = d * 128 + (((mg ^ col) << 3) | sub);
        const f32x4 k4 = kacc[i][j];
        const float e0 = __expf(k4[0]), e1 = __expf(k4[1]);
        const float e2 = __expf(k4[2]), e3 = __expf(k4[3]);
        zacc[j] += (e0 + e1) + (e2 + e3);
        ushort4 pk; pk.x = f2bf(e0); pk.y = f2bf(e1); pk.z = f2bf(e2); pk.w = f2bf(e3);
        const f32x4 v4 = vacc[i][j];
        ushort4 vk; vk.x = f2bf(v4[0]); vk.y = f2bf(v4[1]); vk.z = f2bf(v4[2]); vk.w = f2bf(v4[3]);
        *(ushort4*)(Pb + off) = pk;
        *(ushort4*)(Vb + off) = vk;
      }
    }
    __syncthreads();

    // ---- ctx quadrant: wave (dh,eh) computes d in dh*32+[0,32), e in eh*32+[0,32) over 128 m
#pragma unroll
    for (int kk = 0; kk < 4; ++kk) {
      const int mg = kk * 4 + quad;
      bf16x8 pa[2], vb[2];
#pragma unroll
      for (int i = 0; i < 2; ++i) {
        const int d = dh * 32 + i * 16 + col;
        pa[i] = *(const bf16x8*)(Pb + d * 128 + ((mg ^ col) << 3));
      }
#pragma unroll
      for (int j = 0; j < 2; ++j) {
        const int e = eh * 32 + j * 16 + col;
        vb[j] = *(const bf16x8*)(Vb + e * 128 + ((mg ^ col) << 3));
      }
#pragma unroll
      for (int i = 0; i < 2; ++i)
#pragma unroll
        for (int j = 0; j < 2; ++j) cacc[i][j] = mfma16(pa[i], vb[j], cacc[i][j]);
    }
  }

  // ---- Z: reduce over quads (shfl), then over waves (LDS) ----
#pragma unroll
  for (int j = 0; j < 4; ++j) {
    float s = zacc[j];
    s += __shfl_xor(s, 16); s += __shfl_xor(s, 32);
    if (quad == 0) zred[w][j * 16 + col] = s;
  }
  __syncthreads();

  const int bh = b * H + h;
  float* cp = ctx_part + ((size_t)bh * 16 + mt) * 4096;
#pragma unroll
  for (int i = 0; i < 2; ++i)
#pragma unroll
    for (int j = 0; j < 2; ++j)
#pragma unroll
      for (int r = 0; r < 4; ++r) {
        const int d = dh * 32 + i * 16 + quad * 4 + r;
        const int e = eh * 32 + j * 16 + col;
        cp[d * 64 + e] = cacc[i][j][r];
      }
  if (tid < 64)
    z_part[((size_t)bh * 16 + mt) * 64 + tid] =
        (zred[0][tid] + zred[1][tid]) + (zred[2][tid] + zred[3][tid]);
}

// ---------------------------------------------------------------------------
// Kernel 2 (fused combine + A): per bh:
//   ct[d][e] = sum_mt ctx_part;  zs[d] = SCALE / sum_mt z_part
//   A[b][h*64+e][c] = sum_d ct[d][e] * (zs[d] * Wq[h*64+d, c])
// ---------------------------------------------------------------------------
__global__ __launch_bounds__(256) void a_kernel(
    const float* __restrict__ ctx_part, const float* __restrict__ z_part,
    const float* __restrict__ Wq, float* __restrict__ A)   // [B][HID][C]
{
  const int bh = blockIdx.x, tid = threadIdx.x;
  const int b = bh >> 3, h = bh & 7;
  __shared__ float ct[64 * 65];   // [d][e]
  __shared__ float zs[64];
  __shared__ float wq[64 * 68];   // [d][c-tile], pre-scaled by zs[d]
  const float* cp = ctx_part + (size_t)bh * 16 * 4096;
  for (int g = tid; g < 1024; g += 256) {
    f32x4 s = {0.f, 0.f, 0.f, 0.f};
    for (int p = 0; p < 16; ++p) s += *(const f32x4*)(cp + (size_t)p * 4096 + g * 4);
    const int d = g >> 4, e = (g & 15) << 2;
    ct[d * 65 + e] = s[0]; ct[d * 65 + e + 1] = s[1];
    ct[d * 65 + e + 2] = s[2]; ct[d * 65 + e + 3] = s[3];
  }
  if (tid < 64) {
    float z = 0.f;
    for (int p = 0; p < 16; ++p) z += z_part[((size_t)bh * 16 + p) * 64 + tid];
    zs[tid] = SCALE / z;
  }
  const int e = tid & 63, co = tid >> 6;
  for (int cti = 0; cti < 4; ++cti) {
    const int c0 = cti << 6;
    __syncthreads();
    for (int r = 0; r < 16; ++r) {
      const int idx = tid + (r << 8);
      const int d = idx >> 6;
      wq[d * 68 + (idx & 63)] = Wq[(size_t)(h * 64 + d) * C + c0 + (idx & 63)] * zs[d];
    }
    __syncthreads();
    float acc[16];
#pragma unroll
    for (int k = 0; k < 16; ++k) acc[k] = 0.f;
    for (int d = 0; d < 64; ++d) {
      const float cv = ct[d * 65 + e];
      const float* wr = wq + d * 68 + co * 16;
#pragma unroll
      for (int k = 0; k < 16; ++k) acc[k] += cv * wr[k];
    }
    float* Ar = A + ((size_t)b * HID + h * 64 + e) * C + c0 + co * 16;
#pragma unroll
    for (int k = 0; k < 16; ++k) Ar[k] = acc[k];
  }
}

// ---------------------------------------------------------------------------
// Kernel 3: M[b] = Wo (256x512) @ A[b] (512x256)  -> bf16 [b][o][c]
// ---------------------------------------------------------------------------
__global__ __launch_bounds__(256) void m_kernel(
    const float* __restrict__ A, const float* __restrict__ Wo,
    ushort* __restrict__ M_bf)
{
  const int tile = blockIdx.x, b = blockIdx.y;
  const int o0 = (tile & 3) << 6, c0 = (tile >> 2) << 6;
  const int tid = threadIdx.x, tx = tid & 15, ty = tid >> 4;
  __shared__ float wo_s[16 * 68];  // [k][o]
  __shared__ float a_s[16 * 68];   // [k][c]
  float acc[4][4] = {{0.f}};
  for (int k0 = 0; k0 < HID; k0 += 16) {
    __syncthreads();
    {
      const int o = tid >> 2, koff = (tid & 3) << 2;
      const float4 w4 = *(const float4*)(Wo + (size_t)(o0 + o) * HID + k0 + koff);
      wo_s[(koff + 0) * 68 + o] = w4.x;
      wo_s[(koff + 1) * 68 + o] = w4.y;
      wo_s[(koff + 2) * 68 + o] = w4.z;
      wo_s[(koff + 3) * 68 + o] = w4.w;
      const int kk = tid >> 4, cc = (tid & 15) << 2;
      *(float4*)(a_s + kk * 68 + cc) =
          *(const float4*)(A + ((size_t)b * HID + k0 + kk) * C + c0 + cc);
    }
    __syncthreads();
#pragma unroll
    for (int kc = 0; kc < 16; ++kc) {
      const float4 wv = *(const float4*)(wo_s + kc * 68 + ty * 4);
      const float4 av = *(const float4*)(a_s + kc * 68 + tx * 4);
      const float b0 = av.x, b1 = av.y, b2 = av.z, b3 = av.w;
      acc[0][0] += wv.x * b0; acc[0][1] += wv.x * b1; acc[0][2] += wv.x * b2; acc[0][3] += wv.x * b3;
      acc[1][0] += wv.y * b0; acc[1][1] += wv.y * b1; acc[1][2] += wv.y * b2; acc[1][3] += wv.y * b3;
      acc[2][0] += wv.z * b0; acc[2][1] += wv.z * b1; acc[2][2] += wv.z * b2; acc[2][3] += wv.z * b3;
      acc[3][0] += wv.w * b0; acc[3][1] += wv.w * b1; acc[3][2] += wv.w * b2; acc[3][3] += wv.w * b3;
    }
  }
#pragma unroll
  for (int i = 0; i < 4; ++i) {
    ushort4 r;
    r.x = f2bf(acc[i][0]); r.y = f2bf(acc[i][1]);
    r.z = f2bf(acc[i][2]); r.w = f2bf(acc[i][3]);
    *(ushort4*)(M_bf + ((size_t)b * C + o0 + ty * 4 + i) * C + c0 + tx * 4) = r;
  }
}

// ---------------------------------------------------------------------------
// Kernel 4 (MFMA): out[b] = M_b (256x256) @ X_b (256x4096) + bo
// ---------------------------------------------------------------------------
__global__ __launch_bounds__(256) void out_mfma_kernel(
    const ushort* __restrict__ M_bf,     // [B][C][C] bf16
    const ushort* __restrict__ x_bf,     // [B][N][C] bf16
    const float* __restrict__ bo, float* __restrict__ out)
{
  const int nt = blockIdx.x, ot = blockIdx.y, b = blockIdx.z;
  const int tid = threadIdx.x;
  const int w = tid >> 6, lane = tid & 63;
  const int col = lane & 15, quad = lane >> 4;
  const int o0 = ot * 64;
  const size_t n_base = (size_t)nt * 256 + w * 64;
  const ushort* Ab = M_bf + ((size_t)b * C + o0 + col) * C + quad * 8;
  const ushort* Bb = x_bf + ((size_t)b * N + n_base) * C + quad * 8;

  const f32x4 z4 = {0.f, 0.f, 0.f, 0.f};
  f32x4 acc[4][4];
#pragma unroll
  for (int i = 0; i < 4; ++i)
#pragma unroll
    for (int j = 0; j < 4; ++j) acc[i][j] = z4;

#pragma unroll
  for (int kk = 0; kk < 8; ++kk) {
    bf16x8 af[4], bfz[4];
#pragma unroll
    for (int i = 0; i < 4; ++i) af[i] = *(const bf16x8*)(Ab + (size_t)(i * 16) * C + kk * 32);
#pragma unroll
    for (int j = 0; j < 4; ++j) bfz[j] = *(const bf16x8*)(Bb + (size_t)(j * 16 + col) * C + kk * 32);
#pragma unroll
    for (int i = 0; i < 4; ++i)
#pragma unroll
      for (int j = 0; j < 4; ++j) acc[i][j] = mfma16(af[i], bfz[j], acc[i][j]);
  }

#pragma unroll
  for (int i = 0; i < 4; ++i)
#pragma unroll
    for (int r = 0; r < 4; ++r) {
      const int o = o0 + i * 16 + quad * 4 + r;
      const float bias = bo[o];
      float* op = out + ((size_t)b * C + o) * N + n_base + col;
#pragma unroll
      for (int j = 0; j < 4; ++j) op[j * 16] = acc[i][j][r] + bias;
    }
}

// ---------------------------------------------------------------------------
extern "C" void kernel_launch(void* const* d_in, const int* in_sizes, int n_in,
                              void* d_out, int out_size, void* d_ws, size_t ws_size,
                              hipStream_t stream) {
  const float* x    = (const float*)d_in[0];
  const float* ctxt = (const float*)d_in[1];
  const float* Wq   = (const float*)d_in[2];
  const float* Wk   = (const float*)d_in[3];
  const float* Wv   = (const float*)d_in[4];
  const float* Wo   = (const float*)d_in[5];
  const float* bo   = (const float*)d_in[6];
  float* out = (float*)d_out;

  char* p = (char*)d_ws;
  ushort* ctxt_bf = (ushort*)p;  p += (size_t)B * N * C * 2;        // 16 MB (x_bf aliases)
  ushort* wk_bf   = (ushort*)p;  p += (size_t)HID * C * 2;
  ushort* wv_bf   = (ushort*)p;  p += (size_t)HID * C * 2;
  ushort* M_bf    = (ushort*)p;  p += (size_t)B * C * C * 2;
  float*  z_part  = (float*)p;   p += (size_t)B * H * 16 * 64 * 4;
  float*  ctx_part= (float*)p;   p += (size_t)B * H * 16 * 4096 * 4; // 16.8 MB
  float*  A       = (float*)p;   p += (size_t)B * HID * C * 4;       // 4 MB
  ushort* x_bf    = ctxt_bf;     // reused after kv_mfma_kernel

  // transpose ctxt + cast weights (fused: z=8 slice does the weight cast)
  transpose_cast_kernel<<<dim3(N / 64, C / 64, 9), 256, 0, stream>>>(
      ctxt, ctxt_bf, Wk, Wv, wk_bf, wv_bf);
  kv_mfma_kernel<<<dim3(16, H, B), 256, 0, stream>>>(ctxt_bf, wk_bf, wv_bf, ctx_part, z_part);
  transpose_cast_kernel<<<dim3(N / 64, C / 64, 8), 256, 0, stream>>>(
      x, x_bf, Wk, Wv, wk_bf, wv_bf);
  a_kernel<<<dim3(B * H), 256, 0, stream>>>(ctx_part, z_part, Wq, A);
  m_kernel<<<dim3(16, B), 256, 0, stream>>>(A, Wo, M_bf);
  out_mfma_kernel<<<dim3(N / 256, C / 64, B), 256, 0, stream>>>(M_bf, x_bf, bo, out);
}